// Round 3
// baseline (917.121 us; speedup 1.0000x reference)
//
#include <hip/hip_runtime.h>
#include <hip/hip_bf16.h>
#include <stdint.h>

#define NTOK 4096
#define DIM  1024
#define TOPK 128
#define GBLK 32      // blocks in greedy kernel (all co-resident: 32 << 256 CUs)
#define COLS 128     // token columns per greedy block (GBLK*COLS == NTOK)
#define NEGM -1e30f

// ---------------------------------------------------------------------------
// k_prep: rel[n] = ((-a[n]) - min(-a) + 1e-6) / (max(-a) - min(-a))
// ---------------------------------------------------------------------------
__global__ __launch_bounds__(1024) void k_prep(const float* __restrict__ attn,
                                               float* __restrict__ rel) {
  __shared__ float smx[16], smn[16];
  int tid = threadIdx.x;
  float mx = -3.4e38f, mn = 3.4e38f;
  for (int n = tid; n < NTOK; n += 1024) {
    float a = attn[n];
    mx = fmaxf(mx, a); mn = fminf(mn, a);
  }
  for (int o = 32; o >= 1; o >>= 1) {
    mx = fmaxf(mx, __shfl_down(mx, o, 64));
    mn = fminf(mn, __shfl_down(mn, o, 64));
  }
  if ((tid & 63) == 0) { smx[tid >> 6] = mx; smn[tid >> 6] = mn; }
  __syncthreads();
  if (tid == 0) {
    float MX = smx[0], MN = smn[0];
    for (int w = 1; w < 16; ++w) { MX = fmaxf(MX, smx[w]); MN = fminf(MN, smn[w]); }
    smx[0] = MX; smn[0] = MN;
  }
  __syncthreads();
  float amax = smx[0], amin = smn[0];
  float rmin  = -amax;               // min of (-a)
  float range = (-amin) - rmin;      // max - min
  for (int n = tid; n < NTOK; n += 1024) {
    float r = -attn[n];
    rel[n] = ((r - rmin) + 1e-6f) / range;   // same op order as numpy
  }
}

// ---------------------------------------------------------------------------
// k_norm: xn[row] = x[row] / ||x[row]||   (one block per row, fp32)
// ---------------------------------------------------------------------------
__global__ __launch_bounds__(256) void k_norm(const float* __restrict__ x,
                                              float* __restrict__ xn) {
  __shared__ float ps[4];
  int row = blockIdx.x, tid = threadIdx.x;
  const float4* xr = (const float4*)(x + (size_t)row * DIM);
  float4 v = xr[tid];                           // 256 threads * 4 = 1024 elems
  float s = v.x * v.x + v.y * v.y + v.z * v.z + v.w * v.w;
  for (int o = 32; o >= 1; o >>= 1) s += __shfl_down(s, o, 64);
  if ((tid & 63) == 0) ps[tid >> 6] = s;
  __syncthreads();
  if (tid == 0) ps[0] = ps[0] + ps[1] + ps[2] + ps[3];
  __syncthreads();
  float nrm = sqrtf(ps[0]);                      // IEEE sqrt, then IEEE divide
  float4 o4;
  o4.x = v.x / nrm; o4.y = v.y / nrm; o4.z = v.z / nrm; o4.w = v.w / nrm;
  ((float4*)(xn + (size_t)row * DIM))[tid] = o4;
}

// ---------------------------------------------------------------------------
// k_gemm: ker[i][j] = rel[i] * (xn_i . xn_j) * rel[j], fp32, symmetric.
// 128x128 tile per block (256 thr, 8x8 microtile), BK=8, k-major LDS tiles.
// Upper-triangle tiles only; off-diag tiles write both halves; diagonal
// tiles write upper-only per thread (no duplicate-store race).
// ---------------------------------------------------------------------------
#define BK2 8
__global__ __launch_bounds__(256) void k_gemm(const float* __restrict__ xn,
                                              const float* __restrict__ rel,
                                              float* __restrict__ ker) {
  int bi = blockIdx.y, bj = blockIdx.x;
  if (bi > bj) return;                        // symmetric: skip lower tiles
  __shared__ __align__(16) float As[BK2][132];  // [k][row]
  __shared__ __align__(16) float Bs[BK2][132];
  int tid = threadIdx.x;
  int tx = tid & 15, ty = tid >> 4;           // 16x16 threads, 8x8 micro
  int lrow = tid >> 1, lk = (tid & 1) * 4;    // 128 rows x 2 k-halves
  const float* Ag = xn + (size_t)(bi * 128 + lrow) * DIM + lk;
  const float* Bg = xn + (size_t)(bj * 128 + lrow) * DIM + lk;
  float acc[8][8] = {};
  for (int kt = 0; kt < DIM; kt += BK2) {
    float4 a4 = *(const float4*)(Ag + kt);
    float4 b4 = *(const float4*)(Bg + kt);
    __syncthreads();
    As[lk + 0][lrow] = a4.x; As[lk + 1][lrow] = a4.y;
    As[lk + 2][lrow] = a4.z; As[lk + 3][lrow] = a4.w;
    Bs[lk + 0][lrow] = b4.x; Bs[lk + 1][lrow] = b4.y;
    Bs[lk + 2][lrow] = b4.z; Bs[lk + 3][lrow] = b4.w;
    __syncthreads();
#pragma unroll
    for (int k = 0; k < BK2; ++k) {
      float4 a0 = *(const float4*)&As[k][ty * 8];
      float4 a1 = *(const float4*)&As[k][ty * 8 + 4];
      float4 b0 = *(const float4*)&Bs[k][tx * 8];
      float4 b1 = *(const float4*)&Bs[k][tx * 8 + 4];
      float ar[8] = {a0.x, a0.y, a0.z, a0.w, a1.x, a1.y, a1.z, a1.w};
      float br[8] = {b0.x, b0.y, b0.z, b0.w, b1.x, b1.y, b1.z, b1.w};
#pragma unroll
      for (int r = 0; r < 8; ++r)
#pragma unroll
        for (int c = 0; c < 8; ++c) acc[r][c] += ar[r] * br[c];
    }
  }
  float relr[8], relc[8];
#pragma unroll
  for (int r = 0; r < 8; ++r) relr[r] = rel[bi * 128 + ty * 8 + r];
#pragma unroll
  for (int c = 0; c < 8; ++c) relc[c] = rel[bj * 128 + tx * 8 + c];
#pragma unroll
  for (int r = 0; r < 8; ++r) {
    int gr = bi * 128 + ty * 8 + r;
    // upper half: (acc*relr)*relc, reference's exact op order, float4 stores
    float4 s0, s1;
    s0.x = (acc[r][0] * relr[r]) * relc[0]; s0.y = (acc[r][1] * relr[r]) * relc[1];
    s0.z = (acc[r][2] * relr[r]) * relc[2]; s0.w = (acc[r][3] * relr[r]) * relc[3];
    s1.x = (acc[r][4] * relr[r]) * relc[4]; s1.y = (acc[r][5] * relr[r]) * relc[5];
    s1.z = (acc[r][6] * relr[r]) * relc[6]; s1.w = (acc[r][7] * relr[r]) * relc[7];
    *(float4*)&ker[(size_t)gr * NTOK + bj * 128 + tx * 8]     = s0;
    *(float4*)&ker[(size_t)gr * NTOK + bj * 128 + tx * 8 + 4] = s1;
    if (bi != bj) {
#pragma unroll
      for (int c = 0; c < 8; ++c) {
        int gc = bj * 128 + tx * 8 + c;
        ker[(size_t)gc * NTOK + gr] = (acc[r][c] * relc[c]) * relr[r];
      }
    }
  }
}

// ---------------------------------------------------------------------------
// k_greedy: 128-step greedy DPP MAP. One token column per thread.
// Distributed-slot barrier: block b RELEASE-stores its packed candidate
// (monotonic-float key << 32 | NTOK-1-n; provably nonzero) into
// slots[i*GBLK+b]; 32 lanes ACQUIRE-poll the 32 slots in parallel, wave-
// reduce the max. 2 global round trips per iter (argmax + winner fetch).
// cis is transposed [n][TOPK] so column-j fetch is one coalesced 512B load.
// ---------------------------------------------------------------------------
__global__ __launch_bounds__(128) void k_greedy(const float* __restrict__ ker,
                                                const float* __restrict__ feat,
                                                float* __restrict__ out,
                                                float* __restrict__ cisT,
                                                unsigned long long* __restrict__ slots) {
  __shared__ float cisl[COLS][132];             // [token][t], +4 pad, 66 KB
  __shared__ __align__(16) float colbuf[TOPK];
  __shared__ unsigned long long red2[2];
  __shared__ unsigned long long bw;
  __shared__ int selj[TOPK];
  int tid = threadIdx.x;
  int blk = blockIdx.x;
  int n = blk * COLS + tid;                     // this thread's token
  float di2s = ker[(size_t)n * NTOK + n];       // diag of kernel

  for (int i = 0; i < TOPK; ++i) {
    // ---- local argmax (monotonic float->uint key, first-index tie-break)
    unsigned u = __float_as_uint(di2s);
    unsigned key = (u & 0x80000000u) ? ~u : (u | 0x80000000u);
    unsigned long long pk =
        ((unsigned long long)key << 32) | (unsigned)(NTOK - 1 - n);
    for (int o = 32; o >= 1; o >>= 1) {
      unsigned long long q = __shfl_down(pk, o, 64);
      if (q > pk) pk = q;
    }
    if ((tid & 63) == 0) red2[tid >> 6] = pk;
    __syncthreads();   // all lanes' iter-(i-1) cis stores drained here too
    if (tid == 0) {
      unsigned long long m = red2[0] > red2[1] ? red2[0] : red2[1];
      // release: publishes this block's iter-(i-1) cisT stores + candidate
      __hip_atomic_store(&slots[(size_t)i * GBLK + blk], m, __ATOMIC_RELEASE,
                         __HIP_MEMORY_SCOPE_AGENT);
    }
    // ---- all-to-all: 32 lanes poll the 32 per-block slots in parallel
    unsigned long long v = 0;
    if (tid < GBLK) {
      do {
        v = __hip_atomic_load(&slots[(size_t)i * GBLK + tid], __ATOMIC_ACQUIRE,
                              __HIP_MEMORY_SCOPE_AGENT);
      } while (v == 0);
    }
    if (tid < 64) {
      for (int o = 32; o >= 1; o >>= 1) {
        unsigned long long q = __shfl_down(v, o, 64);
        if (q > v) v = q;
      }
      if (tid == 0) bw = v;
    }
    __syncthreads();
    unsigned long long w = bw;
    int j = NTOK - 1 - (int)(w & 0xffffffffu);
    unsigned kw = (unsigned)(w >> 32);
    unsigned du = (kw & 0x80000000u) ? (kw & 0x7fffffffu) : ~kw;
    float sd = sqrtf(__uint_as_float(du));      // sqrt(di2s[j]) pre-update
    if (tid == 0) selj[i] = j;
    // ---- phase-2 fetches in parallel: ker row j + cis column j
    float kj = ker[(size_t)j * NTOK + n];       // coalesced 512B per block
    if (tid < i)
      colbuf[tid] = __hip_atomic_load(&cisT[(size_t)j * TOPK + tid],
                                      __ATOMIC_RELAXED,
                                      __HIP_MEMORY_SCOPE_AGENT);
    __syncthreads();
    // ---- rank-i projection from block-local fp32 LDS cis (float4 reads)
    float proj;
    {
      const float4* cb4 = (const float4*)colbuf;
      const float4* cl4 = (const float4*)&cisl[tid][0];  // 528B stride, aligned
      float4 p = {0.f, 0.f, 0.f, 0.f};
      int q4 = i >> 2;
      for (int q = 0; q < q4; ++q) {
        float4 a = cb4[q], b = cl4[q];
        p.x += a.x * b.x; p.y += a.y * b.y;
        p.z += a.z * b.z; p.w += a.w * b.w;
      }
      proj = (p.x + p.z) + (p.y + p.w);
      for (int t = q4 * 4; t < i; ++t) proj += colbuf[t] * cisl[tid][t];
    }
    float eis = (kj - proj) / sd;
    // agent-scope store: visible to other XCDs after next slot release
    __hip_atomic_store(&cisT[(size_t)n * TOPK + i], eis, __ATOMIC_RELAXED,
                       __HIP_MEMORY_SCOPE_AGENT);
    cisl[tid][i] = eis;                         // fp32 local (for proj reads)
    di2s -= eis * eis;                          // reference updates all n first,
    if (n == j) di2s = NEGM;                    // then masks j
  }
  __syncthreads();
  // ---- gather output rows: block b copies rows k = b, b+GBLK, ...
  for (int k = blk; k < TOPK; k += GBLK) {
    int j = selj[k];
    const float4* src = (const float4*)(feat + (size_t)j * DIM);
    float4* dst = (float4*)(out + (size_t)k * DIM);
    for (int e = tid; e < DIM / 4; e += COLS) dst[e] = src[e];
  }
}

// ---------------------------------------------------------------------------
// ws layout (bytes):
//   [256,33024)   128*32 u64 candidate slots (zeroed each launch)
//   [49152,65536) rel : 4096 f32
//   [65536,...)   xn  : 4096*1024 f32 (16 MB) -- reused as cisT (4096x128 f32)
//                       after gemm completes (stream-ordered, xn dead then)
//   [65536+16MB)  ker : 4096*4096 f32 (64 MB)
// total ~80.1 MB
// ---------------------------------------------------------------------------
extern "C" void kernel_launch(void* const* d_in, const int* in_sizes, int n_in,
                              void* d_out, int out_size, void* d_ws, size_t ws_size,
                              hipStream_t stream) {
  const float* feat = (const float*)d_in[0];
  const float* attn = (const float*)d_in[1];
  float* out = (float*)d_out;
  char* ws = (char*)d_ws;

  unsigned long long* slots = (unsigned long long*)(ws + 256);
  float* rel = (float*)(ws + 49152);
  float* xn  = (float*)(ws + 65536);
  float* cisT = xn;  // aliases xn: greedy never reads xn, gemm done first
  float* ker = (float*)(ws + 65536 + (size_t)NTOK * DIM * 4);

  hipMemsetAsync(d_ws, 0, 40960, stream);  // zero candidate slots
  k_prep<<<1, 1024, 0, stream>>>(attn, rel);
  k_norm<<<NTOK, 256, 0, stream>>>(feat, xn);
  k_gemm<<<dim3(32, 32), 256, 0, stream>>>(xn, rel, ker);
  k_greedy<<<GBLK, COLS, 0, stream>>>(ker, feat, out, cisT, slots);
}